// Round 6
// baseline (1184.499 us; speedup 1.0000x reference)
//
#include <hip/hip_runtime.h>
#include <hip/hip_fp16.h>
#include <cstddef>

static constexpr int BTOT = 131072;     // B*T
static constexpr int RESO_ = 128;
static constexpr int R2_ = RESO_ * RESO_;   // 16384
static constexpr int NBIN = 4 * R2_;        // B*R2 = 65536
static constexpr int HDIM = 128;
static constexpr int CDIM = 64;

typedef __attribute__((ext_vector_type(8))) short short8;
typedef _Float16 half8 __attribute__((ext_vector_type(8)));
typedef _Float16 half2v __attribute__((ext_vector_type(2)));
typedef __attribute__((ext_vector_type(4))) float floatx4;

__device__ __forceinline__ unsigned short f2h(float f) {
  return __half_as_ushort(__float2half(f));   // RTN
}
__device__ __forceinline__ float h2f(unsigned short h) {
  return __half2float(__ushort_as_half(h));
}
// relu on packed f16: sign bit = bit15, so int16 compare works (+0.0 = 0x0000)
__device__ __forceinline__ short8 relu8(short8 v) {
#pragma unroll
  for (int i = 0; i < 8; ++i) v[i] = (v[i] < (short)0) ? (short)0 : v[i];
  return v;
}

// ---------- bin indices for the 3 planes (+ fused count) ----------
__global__ __launch_bounds__(256) void k_idxcount(const float* __restrict__ p,
                                                  int* __restrict__ idx,
                                                  int* __restrict__ cnt) {
  int pt = blockIdx.x * 256 + threadIdx.x;
  const float DIVC = (float)(1.0 + 0.1 + 1e-5);
  const float HI = (float)(1.0 - 1e-5);
  float x = p[pt * 3 + 0], y = p[pt * 3 + 1], z = p[pt * 3 + 2];
  float nx = fminf(fmaxf(x / DIVC + 0.5f, 0.0f), HI);
  float ny = fminf(fmaxf(y / DIVC + 0.5f, 0.0f), HI);
  float nz = fminf(fmaxf(z / DIVC + 0.5f, 0.0f), HI);
  int ix = (int)(nx * (float)RESO_);
  int iy = (int)(ny * (float)RESO_);
  int iz = (int)(nz * (float)RESO_);
  int off = (pt >> 15) * R2_;
  int i0 = ix + RESO_ * iz + off;   // xz
  int i1 = ix + RESO_ * iy + off;   // xy
  int i2 = iy + RESO_ * iz + off;   // yz
  idx[0 * BTOT + pt] = i0;
  idx[1 * BTOT + pt] = i1;
  idx[2 * BTOT + pt] = i2;
  atomicAdd(&cnt[0 * NBIN + i0], 1);
  atomicAdd(&cnt[1 * NBIN + i1], 1);
  atomicAdd(&cnt[2 * NBIN + i2], 1);
}

__global__ __launch_bounds__(1024) void k_scan(const int* __restrict__ cnt,
                                               int* __restrict__ starts,
                                               int* __restrict__ cursor) {
  __shared__ int part[1024];
  int pl = blockIdx.x;
  int t = threadIdx.x;
  const int* c = cnt + pl * NBIN;
  int base = t * 64;
  int s = 0;
  for (int i = 0; i < 64; ++i) s += c[base + i];
  part[t] = s;
  __syncthreads();
  for (int off = 1; off < 1024; off <<= 1) {
    int v = (t >= off) ? part[t - off] : 0;
    __syncthreads();
    part[t] += v;
    __syncthreads();
  }
  int run = (t == 0) ? 0 : part[t - 1];
  int* st = starts + pl * (NBIN + 1);
  int* cur = cursor + pl * NBIN;
  for (int i = 0; i < 64; ++i) {
    st[base + i] = run;
    cur[base + i] = run;
    run += c[base + i];
  }
  if (t == 1023) st[NBIN] = run;
}

__global__ __launch_bounds__(256) void k_place(const int* __restrict__ idx,
                                               int* __restrict__ cursor,
                                               int* __restrict__ plist) {
  int e = blockIdx.x * 256 + threadIdx.x;    // 3*BTOT
  int pl = e / BTOT, pt = e - pl * BTOT;
  int pos = atomicAdd(&cursor[pl * NBIN + idx[e]], 1);
  plist[(size_t)pl * BTOT + pos] = pt;
}

// ---------- weight packing into MFMA B-fragment order (single f16) ----------
__global__ __launch_bounds__(256) void k_pack(const float* __restrict__ bw0,
                                              const float* __restrict__ bw1,
                                              const float* __restrict__ bws,
                                              unsigned short* __restrict__ P1,
                                              unsigned short* __restrict__ P2) {
  int t = blockIdx.x * 256 + threadIdx.x;
  if (t >= 5 * 20 * 8 * 64) return;
  int lane = t & 63;
  int r = t >> 6;
  int nt = r & 7; r >>= 3;
  int kb20 = r % 20;
  int l = r / 20;
  int quad = lane >> 4;
  int n = nt * 16 + (lane & 15);
#pragma unroll
  for (int j = 0; j < 8; ++j) {
    if (kb20 < 8) {
      int k = kb20 * 32 + quad * 8 + j;
      float v = bw0[((size_t)l * 256 + k) * 128 + n];
      size_t didx = (((size_t)(l * 8 + kb20) * 8 + nt) * 64 + lane) * 8 + j;
      P1[didx] = f2h(v);
    } else {
      int kb = kb20 - 8;
      int k = kb * 32 + quad * 8 + j;
      float v = (k < 256) ? bws[((size_t)l * 256 + k) * 128 + n]
                          : bw1[((size_t)l * 128 + (k - 256)) * 128 + n];
      size_t didx = (((size_t)(l * 12 + kb) * 8 + nt) * 64 + lane) * 8 + j;
      P2[didx] = f2h(v);
    }
  }
}

// ---------- fc_c weight packing: P3[(kb*4+nt)*64+lane][j] ----------
__global__ __launch_bounds__(256) void k_packc(const float* __restrict__ fccw,
                                               unsigned short* __restrict__ P3) {
  int t = blockIdx.x * 256 + threadIdx.x;    // 16 frags x 64 lanes
  if (t >= 16 * 64) return;
  int lane = t & 63;
  int fr = t >> 6;
  int nt = fr & 3, kb = fr >> 2;
  int quad = lane >> 4;
  int n = nt * 16 + (lane & 15);
#pragma unroll
  for (int j = 0; j < 8; ++j) {
    int k = kb * 32 + quad * 8 + j;
    P3[((size_t)fr * 64 + lane) * 8 + j] = f2h(fccw[(size_t)k * 64 + n]);
  }
}

// ---------- list-based pooling max (packed f16 max), 8 bins/wave ----------
__global__ __launch_bounds__(256) void k_poolmax(const unsigned short* __restrict__ net,
                                                 const int* __restrict__ starts,
                                                 const int* __restrict__ plist,
                                                 unsigned short* __restrict__ seg) {
  int tid = threadIdx.x;
  int pl = blockIdx.y;
  int wv = tid >> 6, lane = tid & 63;
  int bin0 = blockIdx.x * 32 + wv * 8;
  const int* st = starts + pl * (NBIN + 1) + bin0;
  int sa[9];
#pragma unroll
  for (int i = 0; i < 9; ++i) sa[i] = st[i];
  const int* pli = plist + (size_t)pl * BTOT;
  half2v v[8];
#pragma unroll
  for (int i = 0; i < 8; ++i) {
    v[i][0] = (_Float16)(-65504.0f);
    v[i][1] = (_Float16)(-65504.0f);
  }
  int lmax = 0;
#pragma unroll
  for (int i = 0; i < 8; ++i) lmax = max(lmax, sa[i + 1] - sa[i]);
  int pid[8];
#pragma unroll
  for (int i = 0; i < 8; ++i) {
    int kk = max(min(sa[i], sa[i + 1] - 1), 0);
    pid[i] = pli[kk];
  }
  for (int k = 0; k < lmax; ++k) {
    unsigned u[8];
#pragma unroll
    for (int i = 0; i < 8; ++i)
      u[i] = *(const unsigned*)(net + (size_t)pid[i] * 128 + lane * 2);
    if (k + 1 < lmax) {
#pragma unroll
      for (int i = 0; i < 8; ++i) {
        int t = sa[i] + k + 1;
        int kk = max(min(t, sa[i + 1] - 1), 0);
        pid[i] = pli[kk];
      }
    }
#pragma unroll
    for (int i = 0; i < 8; ++i) {
      if (sa[i] + k < sa[i + 1]) {
        half2v h = *(half2v*)&u[i];
        v[i] = __builtin_elementwise_max(v[i], h);  // v_pk_max_f16
      }
    }
  }
#pragma unroll
  for (int i = 0; i < 8; ++i) {
    if (sa[i + 1] > sa[i]) {               // empty bins never gathered
      *(unsigned*)(seg + ((size_t)pl * NBIN + bin0 + i) * 128 + lane * 2) =
          *(unsigned*)&v[i];
    }
  }
}

// ---------- persistent fused resblock, 4 tiles/block, cross-tile pipeline ----
// 1024 blocks x 4 tiles of 32 rows. Per tile:
//   stage1 (+issue next tile's global loads into regs)
//   th-epilogue -> stage2 part1 (kb0..7, xh only) -> BARRIER
//   commit next xh <- regs -> stage2 part2 (kb8..11, th) -> store -> BARRIER
// Gather latency (~1200cyc) hides under stage1+part1 MFMA; full-gather stall
// paid once per block (prologue) instead of once per 32 rows.
// MODE 2 = fc_pos fused first layer; LAST = fused fc_c (net routed via th).
#define LD_P1(kb, nti) \
  (((const short8*)P1)[(size_t)(((kb) * 8 + cg * 2 + (nti)) * 64 + lane)])
#define LD_P2(kb, nti) \
  (((const short8*)P2)[(size_t)(((kb) * 8 + cg * 2 + (nti)) * 64 + lane)])
#define MFMA16(a, b, c) __builtin_amdgcn_mfma_f32_16x16x32_f16((a), (b), (c), 0, 0, 0)

template <int MODE, int LAST>
__global__ __launch_bounds__(256, 4) void k_resblock_t(
    const float* __restrict__ p, const float* __restrict__ fcw,
    const float* __restrict__ fcb,
    unsigned short* __restrict__ netA, const unsigned short* __restrict__ segB,
    const int* __restrict__ idx,
    const unsigned short* __restrict__ P1, const unsigned short* __restrict__ P2,
    const float* __restrict__ b0, const float* __restrict__ b1,
    const unsigned short* __restrict__ P3, const float* __restrict__ bc,
    unsigned short* __restrict__ cOut) {
  constexpr int NT = 4;
  __shared__ __align__(16) unsigned short xh[32][264];
  __shared__ __align__(16) unsigned short th[32][136];
  int tid = threadIdx.x;
  int colg = (tid & 31) * 8;          // staging col group
  int rbase = tid >> 5;               // staging rows rbase + {0,8,16,24}
  int lane = tid & 63;
  int cg = tid >> 6;                  // col quarter [0,4)
  int quad = lane >> 4;
  int m0 = lane & 15;

  short8 sreg[12];                    // staging regs (netA: [0..3]; gather: 12)
  float pv[12];                       // MODE2: p values (4 rows x 3)
  float wv0[8], wv1[8], wv2[8], bvv[8];
  if (MODE == 2) {
#pragma unroll
    for (int j = 0; j < 8; ++j) {
      wv0[j] = fcw[colg + j];
      wv1[j] = fcw[256 + colg + j];
      wv2[j] = fcw[512 + colg + j];
      bvv[j] = fcb[colg + j];
    }
  }

  auto stage_issue = [&](int tile) {
    int r0 = tile * 32;
    if (MODE == 2) {
#pragma unroll
      for (int i = 0; i < 4; ++i) {
        int grow = r0 + rbase + i * 8;
#pragma unroll
        for (int j = 0; j < 3; ++j) pv[i * 3 + j] = p[(size_t)grow * 3 + j];
      }
    } else if (colg < 128) {
#pragma unroll
      for (int i = 0; i < 4; ++i) {
        int grow = r0 + rbase + i * 8;
        sreg[i] = *(const short8*)(netA + (size_t)grow * 128 + colg);
      }
    } else {
      int cc = colg - 128;
      int i0[4], i1[4], i2[4];
#pragma unroll
      for (int i = 0; i < 4; ++i) {
        int grow = r0 + rbase + i * 8;
        i0[i] = idx[grow];
        i1[i] = idx[BTOT + grow];
        i2[i] = idx[2 * BTOT + grow];
      }
#pragma unroll
      for (int i = 0; i < 4; ++i) {
        sreg[i * 3 + 0] = *(const short8*)(segB + (size_t)i0[i] * 128 + cc);
        sreg[i * 3 + 1] = *(const short8*)(segB + (size_t)NBIN * 128 + (size_t)i1[i] * 128 + cc);
        sreg[i * 3 + 2] = *(const short8*)(segB + (size_t)2 * NBIN * 128 + (size_t)i2[i] * 128 + cc);
      }
    }
  };

  auto stage_commit = [&]() {
    if (MODE == 2) {
#pragma unroll
      for (int i = 0; i < 4; ++i) {
        short8 o;
#pragma unroll
        for (int j = 0; j < 8; ++j)
          o[j] = (short)f2h(bvv[j] + pv[i * 3 + 0] * wv0[j] +
                            pv[i * 3 + 1] * wv1[j] + pv[i * 3 + 2] * wv2[j]);
        *(short8*)&xh[rbase + i * 8][colg] = o;
      }
    } else if (colg < 128) {
#pragma unroll
      for (int i = 0; i < 4; ++i)
        *(short8*)&xh[rbase + i * 8][colg] = sreg[i];
    } else {
#pragma unroll
      for (int i = 0; i < 4; ++i) {
        half8 s = *(half8*)&sreg[i * 3 + 0] + *(half8*)&sreg[i * 3 + 1] +
                  *(half8*)&sreg[i * 3 + 2];
        *(short8*)&xh[rbase + i * 8][colg] = *(short8*)&s;
      }
    }
  };

  int tbase = blockIdx.x * NT;
  stage_issue(tbase);
  stage_commit();
  __syncthreads();

  for (int t = 0; t < NT; ++t) {
    int rows0 = (tbase + t) * 32;

    // ---- stage1: tt = relu(x) @ w0 + b0 (depth-2 W / depth-1 A prefetch) ----
    floatx4 acc[2][2] = {};
    {
      if (t + 1 < NT) stage_issue(tbase + t + 1);   // regs only; hides ~1200cyc
      short8 cw0 = LD_P1(0, 0), cw1 = LD_P1(0, 1);
      short8 nw0 = LD_P1(1, 0), nw1 = LD_P1(1, 1);
      short8 cx0 = *(const short8*)&xh[m0][quad * 8];
      short8 cx1 = *(const short8*)&xh[m0 + 16][quad * 8];
#pragma unroll
      for (int kb = 0; kb < 8; ++kb) {
        short8 nnw0, nnw1, nx0, nx1;
        if (kb + 2 < 8) { nnw0 = LD_P1(kb + 2, 0); nnw1 = LD_P1(kb + 2, 1); }
        if (kb + 1 < 8) {
          nx0 = *(const short8*)&xh[m0][(kb + 1) * 32 + quad * 8];
          nx1 = *(const short8*)&xh[m0 + 16][(kb + 1) * 32 + quad * 8];
        }
        short8 as0 = relu8(cx0), as1 = relu8(cx1);
        half8 a0 = *(half8*)&as0, a1 = *(half8*)&as1;
        half8 b0v = *(half8*)&cw0, b1v = *(half8*)&cw1;
        acc[0][0] = MFMA16(a0, b0v, acc[0][0]);
        acc[1][0] = MFMA16(a1, b0v, acc[1][0]);
        acc[0][1] = MFMA16(a0, b1v, acc[0][1]);
        acc[1][1] = MFMA16(a1, b1v, acc[1][1]);
        cw0 = nw0; cw1 = nw1; nw0 = nnw0; nw1 = nnw1;
        cx0 = nx0; cx1 = nx1;
      }
    }
    // stage2 weight prefetch issued before th-epilogue VALU (hide L2 latency)
    short8 cw0 = LD_P2(0, 0), cw1 = LD_P2(0, 1);
    short8 nw0 = LD_P2(1, 0), nw1 = LD_P2(1, 1);
    // th-epilogue: bias + relu -> th (f16)
#pragma unroll
    for (int rs = 0; rs < 2; ++rs) {
#pragma unroll
      for (int nti = 0; nti < 2; ++nti) {
        int col = cg * 32 + nti * 16 + m0;
        float bb = b0[col];
#pragma unroll
        for (int r = 0; r < 4; ++r) {
          int row = rs * 16 + quad * 4 + r;
          th[row][col] = f2h(fmaxf(acc[rs][nti][r] + bb, 0.0f));
        }
      }
    }

    // ---- stage2 part1: kb 0..7 (xh only; th not needed -> no barrier yet) ----
    floatx4 acc2[2][2] = {};
    {
      short8 cx0 = *(const short8*)&xh[m0][quad * 8];
      short8 cx1 = *(const short8*)&xh[m0 + 16][quad * 8];
#pragma unroll
      for (int kb = 0; kb < 8; ++kb) {
        short8 nnw0, nnw1, nx0, nx1;
        { nnw0 = LD_P2(kb + 2, 0); nnw1 = LD_P2(kb + 2, 1); }  // up to kb=9 valid
        if (kb + 1 < 8) {
          nx0 = *(const short8*)&xh[m0][(kb + 1) * 32 + quad * 8];
          nx1 = *(const short8*)&xh[m0 + 16][(kb + 1) * 32 + quad * 8];
        }
        half8 a0 = *(half8*)&cx0, a1 = *(half8*)&cx1;
        half8 b0v = *(half8*)&cw0, b1v = *(half8*)&cw1;
        acc2[0][0] = MFMA16(a0, b0v, acc2[0][0]);
        acc2[1][0] = MFMA16(a1, b0v, acc2[1][0]);
        acc2[0][1] = MFMA16(a0, b1v, acc2[0][1]);
        acc2[1][1] = MFMA16(a1, b1v, acc2[1][1]);
        cw0 = nw0; cw1 = nw1; nw0 = nnw0; nw1 = nnw1;
        cx0 = nx0; cx1 = nx1;
      }
    }
    __syncthreads();   // th visible; xh free for overwrite

    // commit next tile's xh (regs staged during stage1; loads landed by now)
    if (t + 1 < NT) stage_commit();

    // ---- stage2 part2: kb 8..11 (th); weight regs carried in: cw=W8, nw=W9 --
    {
      short8 cx0 = *(const short8*)&th[m0][quad * 8];
      short8 cx1 = *(const short8*)&th[m0 + 16][quad * 8];
#pragma unroll
      for (int kb = 8; kb < 12; ++kb) {
        short8 nnw0, nnw1, nx0, nx1;
        if (kb + 2 < 12) { nnw0 = LD_P2(kb + 2, 0); nnw1 = LD_P2(kb + 2, 1); }
        if (kb + 1 < 12) {
          nx0 = *(const short8*)&th[m0][(kb - 7) * 32 + quad * 8];
          nx1 = *(const short8*)&th[m0 + 16][(kb - 7) * 32 + quad * 8];
        }
        half8 a0 = *(half8*)&cx0, a1 = *(half8*)&cx1;
        half8 b0v = *(half8*)&cw0, b1v = *(half8*)&cw1;
        acc2[0][0] = MFMA16(a0, b0v, acc2[0][0]);
        acc2[1][0] = MFMA16(a1, b0v, acc2[1][0]);
        acc2[0][1] = MFMA16(a0, b1v, acc2[0][1]);
        acc2[1][1] = MFMA16(a1, b1v, acc2[1][1]);
        cw0 = nw0; cw1 = nw1; nw0 = nnw0; nw1 = nnw1;
        cx0 = nx0; cx1 = nx1;
      }
    }

    if (!LAST) {
      // epilogue: bias + f16 store (in-place; block owns rows)
#pragma unroll
      for (int rs = 0; rs < 2; ++rs) {
#pragma unroll
        for (int nti = 0; nti < 2; ++nti) {
          int col = cg * 32 + nti * 16 + m0;
          float bb = b1[col];
#pragma unroll
          for (int r = 0; r < 4; ++r) {
            int row = rows0 + rs * 16 + quad * 4 + r;
            netA[(size_t)row * 128 + col] = f2h(acc2[rs][nti][r] + bb);
          }
        }
      }
      __syncthreads();   // commits visible before next stage1
    } else {
      // fused fc_c: route net through th (xh holds next tile already)
      __syncthreads();   // all waves done reading th (part2)
#pragma unroll
      for (int rs = 0; rs < 2; ++rs) {
#pragma unroll
        for (int nti = 0; nti < 2; ++nti) {
          int col = cg * 32 + nti * 16 + m0;
          float bb = b1[col];
#pragma unroll
          for (int r = 0; r < 4; ++r) {
            int row = rs * 16 + quad * 4 + r;
            th[row][col] = f2h(acc2[rs][nti][r] + bb);
          }
        }
      }
      __syncthreads();
      floatx4 acc3[2] = {};
#pragma unroll
      for (int kb = 0; kb < 4; ++kb) {
        short8 as0 = *(const short8*)&th[m0][kb * 32 + quad * 8];
        short8 as1 = *(const short8*)&th[m0 + 16][kb * 32 + quad * 8];
        short8 bs = *((const short8*)P3 + ((size_t)(kb * 4 + cg) * 64 + lane));
        half8 bw = *(half8*)&bs;
        acc3[0] = MFMA16(*(half8*)&as0, bw, acc3[0]);
        acc3[1] = MFMA16(*(half8*)&as1, bw, acc3[1]);
      }
      int col = cg * 16 + m0;
      float bb = bc[col];
#pragma unroll
      for (int rs = 0; rs < 2; ++rs) {
#pragma unroll
        for (int r = 0; r < 4; ++r) {
          int row = rows0 + rs * 16 + quad * 4 + r;
          cOut[(size_t)row * 64 + col] = f2h(acc3[rs][r] + bb);
        }
      }
      __syncthreads();   // th free before next tile's th-epilogue
    }
  }
}
#undef LD_P1
#undef LD_P2
#undef MFMA16

// ---------- fused list-based scatter-mean + transposed output ----------
__global__ __launch_bounds__(256) void k_meanout(const unsigned short* __restrict__ c,
                                                 const int* __restrict__ starts,
                                                 const int* __restrict__ plist,
                                                 float* __restrict__ out) {
  __shared__ float tile[64][65];
  int tid = threadIdx.x;
  int pb = blockIdx.y;                 // pl*4 + b
  int pl = pb >> 2;
  int b = pb & 3;
  int bin0 = blockIdx.x * 64;
  int w = tid >> 6, lane = tid & 63;
  const int* st = starts + pl * (NBIN + 1) + b * R2_ + bin0 + w * 16;
  const int* pli = plist + (size_t)pl * BTOT;
  for (int grp = 0; grp < 4; ++grp) {
    int sa[5];
#pragma unroll
    for (int i = 0; i < 5; ++i) sa[i] = st[grp * 4 + i];
    float sum[4] = {0.f, 0.f, 0.f, 0.f};
    int lmax = 0;
#pragma unroll
    for (int i = 0; i < 4; ++i) lmax = max(lmax, sa[i + 1] - sa[i]);
    int pid[4];
#pragma unroll
    for (int i = 0; i < 4; ++i) {
      int kk = max(min(sa[i], sa[i + 1] - 1), 0);
      pid[i] = pli[kk];
    }
    for (int k = 0; k < lmax; ++k) {
      unsigned short u[4];
#pragma unroll
      for (int i = 0; i < 4; ++i)
        u[i] = c[(size_t)pid[i] * 64 + lane];
      if (k + 1 < lmax) {
#pragma unroll
        for (int i = 0; i < 4; ++i) {
          int t = sa[i] + k + 1;
          int kk = max(min(t, sa[i + 1] - 1), 0);
          pid[i] = pli[kk];
        }
      }
#pragma unroll
      for (int i = 0; i < 4; ++i) {
        if (sa[i] + k < sa[i + 1]) sum[i] += h2f(u[i]);
      }
    }
#pragma unroll
    for (int i = 0; i < 4; ++i) {
      int lb = w * 16 + grp * 4 + i;
      tile[lb][lane] = sum[i] / fmaxf((float)(sa[i + 1] - sa[i]), 1.0f);
    }
  }
  __syncthreads();
#pragma unroll
  for (int i = 0; i < 16; ++i) {
    int e2 = i * 256 + tid;
    int ch = e2 >> 6, lb = e2 & 63;
    out[((size_t)pb * 64 + ch) * R2_ + bin0 + lb] = tile[lb][ch];
  }
}

extern "C" void kernel_launch(void* const* d_in, const int* in_sizes, int n_in,
                              void* d_out, int out_size, void* d_ws, size_t ws_size,
                              hipStream_t stream) {
  const float* p    = (const float*)d_in[0];
  const float* fcw  = (const float*)d_in[1];
  const float* fcb  = (const float*)d_in[2];
  const float* bw0  = (const float*)d_in[3];
  const float* bb0  = (const float*)d_in[4];
  const float* bw1  = (const float*)d_in[5];
  const float* bb1  = (const float*)d_in[6];
  const float* bws  = (const float*)d_in[7];
  const float* fccw = (const float*)d_in[8];
  const float* fccb = (const float*)d_in[9];
  float* out = (float*)d_out;

  char* ws = (char*)d_ws;
  const size_t P1_LAYER = 8 * 8 * 64 * 8;               // shorts
  const size_t P2_LAYER = 12 * 8 * 64 * 8;              // shorts

  size_t off = 0;
  unsigned short* netA = (unsigned short*)(ws + off); off += (size_t)BTOT * 128 * 2;
  unsigned short* cbuf = (unsigned short*)(ws + off); off += (size_t)BTOT * 64 * 2;
  int*   idx  = (int*)(ws + off);   off += (size_t)3 * BTOT * 4;
  unsigned short* P1 = (unsigned short*)(ws + off); off += 5 * P1_LAYER * 2;
  unsigned short* P2 = (unsigned short*)(ws + off); off += 5 * P2_LAYER * 2;
  unsigned short* P3 = (unsigned short*)(ws + off); off += (size_t)16 * 64 * 8 * 2;
  int* cntb   = (int*)(ws + off); off += (size_t)3 * NBIN * 4;
  int* starts = (int*)(ws + off); off += (size_t)3 * (NBIN + 1) * 4;
  int* cursor = (int*)(ws + off); off += (size_t)3 * NBIN * 4;
  int* plist  = (int*)(ws + off); off += (size_t)3 * BTOT * 4;
  off = (off + 255) & ~(size_t)255;
  unsigned short* seg = (unsigned short*)(ws + off); // 3*NBIN*128*2 = 50.3 MiB

  hipMemsetAsync(cntb, 0, (size_t)3 * NBIN * 4, stream);
  k_idxcount<<<BTOT / 256, 256, 0, stream>>>(p, idx, cntb);
  k_scan<<<3, 1024, 0, stream>>>(cntb, starts, cursor);
  k_place<<<3 * BTOT / 256, 256, 0, stream>>>(idx, cursor, plist);
  k_pack<<<200, 256, 0, stream>>>(bw0, bw1, bws, P1, P2);
  k_packc<<<4, 256, 0, stream>>>(fccw, P3);

  const int NBLK = BTOT / 32 / 4;   // 1024 persistent blocks, 4 tiles each
  for (int blk = 0; blk < 5; ++blk) {
    if (blk > 0) {
      dim3 g(NBIN / 32, 3);
      k_poolmax<<<g, 256, 0, stream>>>(netA, starts, plist, seg);
    }
    const unsigned short* p1 = P1 + (size_t)blk * P1_LAYER;
    const unsigned short* p2 = P2 + (size_t)blk * P2_LAYER;
    const float* bb0l = bb0 + (size_t)blk * 128;
    const float* bb1l = bb1 + (size_t)blk * 128;
    if (blk == 0)
      k_resblock_t<2, 0><<<NBLK, 256, 0, stream>>>(
          p, fcw, fcb, netA, seg, idx, p1, p2, bb0l, bb1l, P3, fccb, nullptr);
    else if (blk < 4)
      k_resblock_t<1, 0><<<NBLK, 256, 0, stream>>>(
          p, fcw, fcb, netA, seg, idx, p1, p2, bb0l, bb1l, P3, fccb, nullptr);
    else
      k_resblock_t<1, 1><<<NBLK, 256, 0, stream>>>(
          p, fcw, fcb, netA, seg, idx, p1, p2, bb0l, bb1l, P3, fccb, cbuf);
  }

  dim3 gm(R2_ / 64, 12);
  k_meanout<<<gm, 256, 0, stream>>>(cbuf, starts, plist, out);
}

// Round 9
// 483.226 us; speedup vs baseline: 2.4512x; 2.4512x over previous
//
#include <hip/hip_runtime.h>
#include <hip/hip_fp16.h>
#include <cstddef>

static constexpr int BTOT = 131072;     // B*T
static constexpr int RESO_ = 128;
static constexpr int R2_ = RESO_ * RESO_;   // 16384
static constexpr int NBIN = 4 * R2_;        // B*R2 = 65536
static constexpr int HDIM = 128;
static constexpr int CDIM = 64;

typedef __attribute__((ext_vector_type(8))) short short8;
typedef __attribute__((ext_vector_type(4))) short short4v;
typedef _Float16 half8 __attribute__((ext_vector_type(8)));
typedef _Float16 half2v __attribute__((ext_vector_type(2)));
typedef __attribute__((ext_vector_type(4))) float floatx4;

__device__ __forceinline__ unsigned short f2h(float f) {
  return __half_as_ushort(__float2half(f));   // RTN
}
__device__ __forceinline__ float h2f(unsigned short h) {
  return __half2float(__ushort_as_half(h));
}
// relu on packed f16: sign bit = bit15, so int16 compare works (+0.0 = 0x0000)
__device__ __forceinline__ short8 relu8(short8 v) {
#pragma unroll
  for (int i = 0; i < 8; ++i) v[i] = (v[i] < (short)0) ? (short)0 : v[i];
  return v;
}

// ---------- bin indices for the 3 planes (+ fused count) ----------
__global__ __launch_bounds__(256) void k_idxcount(const float* __restrict__ p,
                                                  int* __restrict__ idx,
                                                  int* __restrict__ cnt) {
  int pt = blockIdx.x * 256 + threadIdx.x;
  const float DIVC = (float)(1.0 + 0.1 + 1e-5);
  const float HI = (float)(1.0 - 1e-5);
  float x = p[pt * 3 + 0], y = p[pt * 3 + 1], z = p[pt * 3 + 2];
  float nx = fminf(fmaxf(x / DIVC + 0.5f, 0.0f), HI);
  float ny = fminf(fmaxf(y / DIVC + 0.5f, 0.0f), HI);
  float nz = fminf(fmaxf(z / DIVC + 0.5f, 0.0f), HI);
  int ix = (int)(nx * (float)RESO_);
  int iy = (int)(ny * (float)RESO_);
  int iz = (int)(nz * (float)RESO_);
  int off = (pt >> 15) * R2_;
  int i0 = ix + RESO_ * iz + off;   // xz
  int i1 = ix + RESO_ * iy + off;   // xy
  int i2 = iy + RESO_ * iz + off;   // yz
  idx[0 * BTOT + pt] = i0;
  idx[1 * BTOT + pt] = i1;
  idx[2 * BTOT + pt] = i2;
  atomicAdd(&cnt[0 * NBIN + i0], 1);
  atomicAdd(&cnt[1 * NBIN + i1], 1);
  atomicAdd(&cnt[2 * NBIN + i2], 1);
}

__global__ __launch_bounds__(1024) void k_scan(const int* __restrict__ cnt,
                                               int* __restrict__ starts,
                                               int* __restrict__ cursor) {
  __shared__ int part[1024];
  int pl = blockIdx.x;
  int t = threadIdx.x;
  const int* c = cnt + pl * NBIN;
  int base = t * 64;
  int s = 0;
  for (int i = 0; i < 64; ++i) s += c[base + i];
  part[t] = s;
  __syncthreads();
  for (int off = 1; off < 1024; off <<= 1) {
    int v = (t >= off) ? part[t - off] : 0;
    __syncthreads();
    part[t] += v;
    __syncthreads();
  }
  int run = (t == 0) ? 0 : part[t - 1];
  int* st = starts + pl * (NBIN + 1);
  int* cur = cursor + pl * NBIN;
  for (int i = 0; i < 64; ++i) {
    st[base + i] = run;
    cur[base + i] = run;
    run += c[base + i];
  }
  if (t == 1023) st[NBIN] = run;
}

__global__ __launch_bounds__(256) void k_place(const int* __restrict__ idx,
                                               int* __restrict__ cursor,
                                               int* __restrict__ plist) {
  int e = blockIdx.x * 256 + threadIdx.x;    // 3*BTOT
  int pl = e / BTOT, pt = e - pl * BTOT;
  int pos = atomicAdd(&cursor[pl * NBIN + idx[e]], 1);
  plist[(size_t)pl * BTOT + pos] = pt;
}

// ---------- weight packing into MFMA B-fragment order (single f16) ----------
__global__ __launch_bounds__(256) void k_pack(const float* __restrict__ bw0,
                                              const float* __restrict__ bw1,
                                              const float* __restrict__ bws,
                                              unsigned short* __restrict__ P1,
                                              unsigned short* __restrict__ P2) {
  int t = blockIdx.x * 256 + threadIdx.x;
  if (t >= 5 * 20 * 8 * 64) return;
  int lane = t & 63;
  int r = t >> 6;
  int nt = r & 7; r >>= 3;
  int kb20 = r % 20;
  int l = r / 20;
  int quad = lane >> 4;
  int n = nt * 16 + (lane & 15);
#pragma unroll
  for (int j = 0; j < 8; ++j) {
    if (kb20 < 8) {
      int k = kb20 * 32 + quad * 8 + j;
      float v = bw0[((size_t)l * 256 + k) * 128 + n];
      size_t didx = (((size_t)(l * 8 + kb20) * 8 + nt) * 64 + lane) * 8 + j;
      P1[didx] = f2h(v);
    } else {
      int kb = kb20 - 8;
      int k = kb * 32 + quad * 8 + j;
      float v = (k < 256) ? bws[((size_t)l * 256 + k) * 128 + n]
                          : bw1[((size_t)l * 128 + (k - 256)) * 128 + n];
      size_t didx = (((size_t)(l * 12 + kb) * 8 + nt) * 64 + lane) * 8 + j;
      P2[didx] = f2h(v);
    }
  }
}

// ---------- fc_c weight packing: P3[(kb*4+nt)*64+lane][j] ----------
__global__ __launch_bounds__(256) void k_packc(const float* __restrict__ fccw,
                                               unsigned short* __restrict__ P3) {
  int t = blockIdx.x * 256 + threadIdx.x;    // 16 frags x 64 lanes
  if (t >= 16 * 64) return;
  int lane = t & 63;
  int fr = t >> 6;
  int nt = fr & 3, kb = fr >> 2;
  int quad = lane >> 4;
  int n = nt * 16 + (lane & 15);
#pragma unroll
  for (int j = 0; j < 8; ++j) {
    int k = kb * 32 + quad * 8 + j;
    P3[((size_t)fr * 64 + lane) * 8 + j] = f2h(fccw[(size_t)k * 64 + n]);
  }
}

// ---------- list-based pooling max, wide-load version ----------
// grid (NBIN/64, 3); block 256 = 4 waves; wave = 4 groups of 16 lanes.
// Each 16-lane group owns 4 bin-chains; lane loads dwordx4 (8 channels, 16B)
// so ONE VMEM instruction covers 4 bins x 256B = 1KB (was 1 bin x 256B):
// 4x fewer load instructions at identical bytes, 16 rows in flight per wave.
// pid prefetched one iteration ahead (overlap plist + net latency hops).
__global__ __launch_bounds__(256) void k_poolmax(const unsigned short* __restrict__ net,
                                                 const int* __restrict__ starts,
                                                 const int* __restrict__ plist,
                                                 unsigned short* __restrict__ seg) {
  int tid = threadIdx.x;
  int pl = blockIdx.y;
  int wv = tid >> 6, lane = tid & 63;
  int g = lane >> 4, lc = lane & 15;
  int bin0 = blockIdx.x * 64 + wv * 16 + g * 4;
  const int* st = starts + pl * (NBIN + 1) + bin0;
  int sa[5];
#pragma unroll
  for (int i = 0; i < 5; ++i) sa[i] = st[i];
  const int* pli = plist + (size_t)pl * BTOT;
  half8 v[4];
#pragma unroll
  for (int i = 0; i < 4; ++i) {
#pragma unroll
    for (int j = 0; j < 8; ++j) v[i][j] = (_Float16)(-65504.0f);
  }
  int lmax = 0;
#pragma unroll
  for (int i = 0; i < 4; ++i) lmax = max(lmax, sa[i + 1] - sa[i]);
  int pid[4];
#pragma unroll
  for (int i = 0; i < 4; ++i) {
    int kk = max(min(sa[i], sa[i + 1] - 1), 0);
    pid[i] = pli[kk];
  }
  for (int k = 0; k < lmax; ++k) {
    short8 u[4];
#pragma unroll
    for (int i = 0; i < 4; ++i)
      u[i] = *(const short8*)(net + (size_t)pid[i] * 128 + lc * 8);
    if (k + 1 < lmax) {
#pragma unroll
      for (int i = 0; i < 4; ++i) {
        int kk = max(min(sa[i] + k + 1, sa[i + 1] - 1), 0);
        pid[i] = pli[kk];
      }
    }
#pragma unroll
    for (int i = 0; i < 4; ++i) {
      if (sa[i] + k < sa[i + 1]) {
        half8 h = *(half8*)&u[i];
        v[i] = __builtin_elementwise_max(v[i], h);  // 4x v_pk_max_f16
      }
    }
  }
#pragma unroll
  for (int i = 0; i < 4; ++i) {
    if (sa[i + 1] > sa[i]) {               // empty bins never gathered
      *(short8*)(seg + ((size_t)pl * NBIN + bin0 + i) * 128 + lc * 8) =
          *(short8*)&v[i];
    }
  }
}

// ---------- fused resblock with in-kernel 3-plane gather (all f16) ----------
// VERBATIM round-5 kernel (verified 48.4us, absmax 0.015625). The persistent
// cross-tile variant (rounds 6-7) is abandoned: r6 spilled to scratch (2.3x
// regression), r7's de-spill failed correctness with a timing-dependent
// divergence not attributable by inspection -> branch closed.
__global__ __launch_bounds__(256, 4) void k_resblock(
    const float* __restrict__ p, const float* __restrict__ fcw,
    const float* __restrict__ fcb,
    unsigned short* __restrict__ netA, const unsigned short* __restrict__ segB,
    const int* __restrict__ idx, int mode,
    const unsigned short* __restrict__ P1, const unsigned short* __restrict__ P2,
    const float* __restrict__ b0, const float* __restrict__ b1,
    const unsigned short* __restrict__ P3, const float* __restrict__ bc,
    unsigned short* __restrict__ cOut) {
  __shared__ __align__(16) unsigned short xh[32][264];
  __shared__ __align__(16) unsigned short th[32][136];
  __shared__ float pp[96];
  int tid = threadIdx.x;
  int rows0 = blockIdx.x * 32;

  if (mode == 2) {
    // fused fc_pos: x[row][0..256) = p[row] @ fcw + fcb, f16 RTN
    if (tid < 96) pp[tid] = p[(size_t)rows0 * 3 + tid];
    __syncthreads();
    int g = (tid & 31) * 8;              // col group of 8
    int rh = tid >> 5;                   // row chunk [0,8) -> 4 rows each
    float wv0[8], wv1[8], wv2[8], bv[8];
#pragma unroll
    for (int j = 0; j < 8; ++j) {
      wv0[j] = fcw[g + j];
      wv1[j] = fcw[256 + g + j];
      wv2[j] = fcw[512 + g + j];
      bv[j] = fcb[g + j];
    }
#pragma unroll
    for (int rr = 0; rr < 4; ++rr) {
      int row = rh * 4 + rr;
      float x0 = pp[row * 3 + 0], x1 = pp[row * 3 + 1], x2 = pp[row * 3 + 2];
      short8 o;
#pragma unroll
      for (int j = 0; j < 8; ++j)
        o[j] = (short)f2h(bv[j] + x0 * wv0[j] + x1 * wv1[j] + x2 * wv2[j]);
      *(short8*)&xh[row][g] = o;
    }
  } else {
    // stage A: col group is invariant over a thread's 4 row-iterations,
    // so split into pure-netA threads and pure-gather threads; gather
    // threads issue all 12 seg loads before any consume.
    int col = (tid & 31) * 8;
    int rbase = tid >> 5;                // rows rbase + {0,8,16,24}
    if (col < 128) {
#pragma unroll
      for (int i = 0; i < 4; ++i) {
        int row = rbase + i * 8;
        *(short8*)&xh[row][col] =
            *(const short8*)(netA + (size_t)(rows0 + row) * 128 + col);
      }
    } else {
      int cc = col - 128;
      int i0[4], i1[4], i2[4];
#pragma unroll
      for (int i = 0; i < 4; ++i) {
        int grow = rows0 + rbase + i * 8;
        i0[i] = idx[grow];
        i1[i] = idx[BTOT + grow];
        i2[i] = idx[2 * BTOT + grow];
      }
      short8 av[4], bv8[4], cv8[4];
#pragma unroll
      for (int i = 0; i < 4; ++i) {
        av[i] = *(const short8*)(segB + (size_t)i0[i] * 128 + cc);
        bv8[i] = *(const short8*)(segB + (size_t)NBIN * 128 + (size_t)i1[i] * 128 + cc);
        cv8[i] = *(const short8*)(segB + (size_t)2 * NBIN * 128 + (size_t)i2[i] * 128 + cc);
      }
#pragma unroll
      for (int i = 0; i < 4; ++i) {
        half8 s = *(half8*)&av[i] + *(half8*)&bv8[i] + *(half8*)&cv8[i];
        *(short8*)&xh[rbase + i * 8][col] = *(short8*)&s;
      }
    }
  }
  __syncthreads();

  int lane = tid & 63;
  int cg = tid >> 6;               // col quarter [0,4)
  int quad = lane >> 4;
  int m0 = lane & 15;

#define LD_P1(kb, nti) \
  (((const short8*)P1)[(size_t)(((kb) * 8 + cg * 2 + (nti)) * 64 + lane)])
#define LD_P2(kb, nti) \
  (((const short8*)P2)[(size_t)(((kb) * 8 + cg * 2 + (nti)) * 64 + lane)])
#define MFMA16(a, b, c) __builtin_amdgcn_mfma_f32_16x16x32_f16((a), (b), (c), 0, 0, 0)

  // ---- stage 1: t = relu(x) @ w0 + b0 (depth-2 W prefetch, depth-1 A) ----
  floatx4 acc[2][2] = {};
  {
    short8 cw0 = LD_P1(0, 0), cw1 = LD_P1(0, 1);
    short8 nw0 = LD_P1(1, 0), nw1 = LD_P1(1, 1);
    short8 cx0 = *(const short8*)&xh[m0][quad * 8];
    short8 cx1 = *(const short8*)&xh[m0 + 16][quad * 8];
#pragma unroll
    for (int kb = 0; kb < 8; ++kb) {
      short8 nnw0, nnw1, nx0, nx1;
      if (kb + 2 < 8) { nnw0 = LD_P1(kb + 2, 0); nnw1 = LD_P1(kb + 2, 1); }
      if (kb + 1 < 8) {
        nx0 = *(const short8*)&xh[m0][(kb + 1) * 32 + quad * 8];
        nx1 = *(const short8*)&xh[m0 + 16][(kb + 1) * 32 + quad * 8];
      }
      short8 as0 = relu8(cx0), as1 = relu8(cx1);
      half8 a0 = *(half8*)&as0, a1 = *(half8*)&as1;
      half8 b0v = *(half8*)&cw0, b1v = *(half8*)&cw1;
      acc[0][0] = MFMA16(a0, b0v, acc[0][0]);
      acc[1][0] = MFMA16(a1, b0v, acc[1][0]);
      acc[0][1] = MFMA16(a0, b1v, acc[0][1]);
      acc[1][1] = MFMA16(a1, b1v, acc[1][1]);
      cw0 = nw0; cw1 = nw1; nw0 = nnw0; nw1 = nnw1;
      cx0 = nx0; cx1 = nx1;
    }
  }
  // epilogue 1: bias + relu -> th (f16)
#pragma unroll
  for (int rs = 0; rs < 2; ++rs) {
#pragma unroll
    for (int nti = 0; nti < 2; ++nti) {
      int col = cg * 32 + nti * 16 + m0;
      float bb = b0[col];
#pragma unroll
      for (int r = 0; r < 4; ++r) {
        int row = rs * 16 + quad * 4 + r;
        th[row][col] = f2h(fmaxf(acc[rs][nti][r] + bb, 0.0f));
      }
    }
  }
  __syncthreads();

  // ---- stage 2: out = x @ ws + relu_t @ w1 + b1 ----
#define LD_A2(kb, off)                                              \
  ((kb) < 8 ? *(const short8*)&xh[m0 + (off)][(kb) * 32 + quad * 8] \
            : *(const short8*)&th[m0 + (off)][((kb) - 8) * 32 + quad * 8])
  floatx4 acc2[2][2] = {};
  {
    short8 cw0 = LD_P2(0, 0), cw1 = LD_P2(0, 1);
    short8 nw0 = LD_P2(1, 0), nw1 = LD_P2(1, 1);
    short8 cx0 = LD_A2(0, 0);
    short8 cx1 = LD_A2(0, 16);
#pragma unroll
    for (int kb = 0; kb < 12; ++kb) {
      short8 nnw0, nnw1, nx0, nx1;
      if (kb + 2 < 12) { nnw0 = LD_P2(kb + 2, 0); nnw1 = LD_P2(kb + 2, 1); }
      if (kb + 1 < 12) {
        nx0 = LD_A2(kb + 1, 0);
        nx1 = LD_A2(kb + 1, 16);
      }
      half8 a0 = *(half8*)&cx0, a1 = *(half8*)&cx1;
      half8 b0v = *(half8*)&cw0, b1v = *(half8*)&cw1;
      acc2[0][0] = MFMA16(a0, b0v, acc2[0][0]);
      acc2[1][0] = MFMA16(a1, b0v, acc2[1][0]);
      acc2[0][1] = MFMA16(a0, b1v, acc2[0][1]);
      acc2[1][1] = MFMA16(a1, b1v, acc2[1][1]);
      cw0 = nw0; cw1 = nw1; nw0 = nnw0; nw1 = nnw1;
      cx0 = nx0; cx1 = nx1;
    }
  }

  if (!cOut) {
    // epilogue 2: bias + f16 store (in-place; block owns rows)
#pragma unroll
    for (int rs = 0; rs < 2; ++rs) {
#pragma unroll
      for (int nti = 0; nti < 2; ++nti) {
        int col = cg * 32 + nti * 16 + m0;
        float bb = b1[col];
#pragma unroll
        for (int r = 0; r < 4; ++r) {
          int row = rows0 + rs * 16 + quad * 4 + r;
          netA[(size_t)row * 128 + col] = f2h(acc2[rs][nti][r] + bb);
        }
      }
    }
  } else {
    // fused fc_c: round-trip net through xh, then 8 MFMAs per wave
    __syncthreads();                     // all waves done reading xh/th
#pragma unroll
    for (int rs = 0; rs < 2; ++rs) {
#pragma unroll
      for (int nti = 0; nti < 2; ++nti) {
        int col = cg * 32 + nti * 16 + m0;
        float bb = b1[col];
#pragma unroll
        for (int r = 0; r < 4; ++r) {
          int row = rs * 16 + quad * 4 + r;
          xh[row][col] = f2h(acc2[rs][nti][r] + bb);
        }
      }
    }
    __syncthreads();
    floatx4 acc3[2] = {};
#pragma unroll
    for (int kb = 0; kb < 4; ++kb) {
      short8 as0 = *(const short8*)&xh[m0][kb * 32 + quad * 8];
      short8 as1 = *(const short8*)&xh[m0 + 16][kb * 32 + quad * 8];
      short8 bs = *((const short8*)P3 + ((size_t)(kb * 4 + cg) * 64 + lane));
      half8 bw = *(half8*)&bs;
      acc3[0] = MFMA16(*(half8*)&as0, bw, acc3[0]);
      acc3[1] = MFMA16(*(half8*)&as1, bw, acc3[1]);
    }
    int col = cg * 16 + m0;
    float bb = bc[col];
#pragma unroll
    for (int rs = 0; rs < 2; ++rs) {
#pragma unroll
      for (int r = 0; r < 4; ++r) {
        int row = rows0 + rs * 16 + quad * 4 + r;
        cOut[(size_t)row * 64 + col] = f2h(acc3[rs][r] + bb);
      }
    }
  }
#undef LD_P1
#undef LD_P2
#undef LD_A2
#undef MFMA16
}

// ---------- fused list-based scatter-mean + transposed output ----------
// Wide-load version: wave = 4 groups of 16 lanes; each group owns 4 bin
// chains; lane loads dwordx2 (4 channels, 8B) so one VMEM instruction covers
// 4 bins x 128B (was 1 bin x 128B). pid prefetched one iteration ahead.
__global__ __launch_bounds__(256) void k_meanout(const unsigned short* __restrict__ c,
                                                 const int* __restrict__ starts,
                                                 const int* __restrict__ plist,
                                                 float* __restrict__ out) {
  __shared__ float tile[64][65];
  int tid = threadIdx.x;
  int pb = blockIdx.y;                 // pl*4 + b
  int pl = pb >> 2;
  int b = pb & 3;
  int bin0 = blockIdx.x * 64;
  int w = tid >> 6, lane = tid & 63;
  int g = lane >> 4, lc = lane & 15;
  const int* st = starts + pl * (NBIN + 1) + b * R2_ + bin0 + w * 16 + g * 4;
  const int* pli = plist + (size_t)pl * BTOT;
  int sa[5];
#pragma unroll
  for (int i = 0; i < 5; ++i) sa[i] = st[i];
  floatx4 sum[4] = {};
  int lmax = 0;
#pragma unroll
  for (int i = 0; i < 4; ++i) lmax = max(lmax, sa[i + 1] - sa[i]);
  int pid[4];
#pragma unroll
  for (int i = 0; i < 4; ++i) {
    int kk = max(min(sa[i], sa[i + 1] - 1), 0);
    pid[i] = pli[kk];
  }
  for (int k = 0; k < lmax; ++k) {
    short4v u[4];
#pragma unroll
    for (int i = 0; i < 4; ++i)
      u[i] = *(const short4v*)(c + (size_t)pid[i] * 64 + lc * 4);
    if (k + 1 < lmax) {
#pragma unroll
      for (int i = 0; i < 4; ++i) {
        int kk = max(min(sa[i] + k + 1, sa[i + 1] - 1), 0);
        pid[i] = pli[kk];
      }
    }
#pragma unroll
    for (int i = 0; i < 4; ++i) {
      if (sa[i] + k < sa[i + 1]) {
#pragma unroll
        for (int j = 0; j < 4; ++j)
          sum[i][j] += h2f((unsigned short)u[i][j]);
      }
    }
  }
#pragma unroll
  for (int i = 0; i < 4; ++i) {
    int lb = w * 16 + g * 4 + i;
    float cnt = fmaxf((float)(sa[i + 1] - sa[i]), 1.0f);
#pragma unroll
    for (int j = 0; j < 4; ++j)
      tile[lb][lc * 4 + j] = sum[i][j] / cnt;
  }
  __syncthreads();
#pragma unroll
  for (int i = 0; i < 16; ++i) {
    int e2 = i * 256 + tid;
    int ch = e2 >> 6, lb = e2 & 63;
    out[((size_t)pb * 64 + ch) * R2_ + bin0 + lb] = tile[lb][ch];
  }
}

extern "C" void kernel_launch(void* const* d_in, const int* in_sizes, int n_in,
                              void* d_out, int out_size, void* d_ws, size_t ws_size,
                              hipStream_t stream) {
  const float* p    = (const float*)d_in[0];
  const float* fcw  = (const float*)d_in[1];
  const float* fcb  = (const float*)d_in[2];
  const float* bw0  = (const float*)d_in[3];
  const float* bb0  = (const float*)d_in[4];
  const float* bw1  = (const float*)d_in[5];
  const float* bb1  = (const float*)d_in[6];
  const float* bws  = (const float*)d_in[7];
  const float* fccw = (const float*)d_in[8];
  const float* fccb = (const float*)d_in[9];
  float* out = (float*)d_out;

  char* ws = (char*)d_ws;
  const size_t P1_LAYER = 8 * 8 * 64 * 8;               // shorts
  const size_t P2_LAYER = 12 * 8 * 64 * 8;              // shorts

  size_t off = 0;
  unsigned short* netA = (unsigned short*)(ws + off); off += (size_t)BTOT * 128 * 2;
  unsigned short* cbuf = (unsigned short*)(ws + off); off += (size_t)BTOT * 64 * 2;
  int*   idx  = (int*)(ws + off);   off += (size_t)3 * BTOT * 4;
  unsigned short* P1 = (unsigned short*)(ws + off); off += 5 * P1_LAYER * 2;
  unsigned short* P2 = (unsigned short*)(ws + off); off += 5 * P2_LAYER * 2;
  unsigned short* P3 = (unsigned short*)(ws + off); off += (size_t)16 * 64 * 8 * 2;
  int* cntb   = (int*)(ws + off); off += (size_t)3 * NBIN * 4;
  int* starts = (int*)(ws + off); off += (size_t)3 * (NBIN + 1) * 4;
  int* cursor = (int*)(ws + off); off += (size_t)3 * NBIN * 4;
  int* plist  = (int*)(ws + off); off += (size_t)3 * BTOT * 4;
  off = (off + 255) & ~(size_t)255;
  unsigned short* seg = (unsigned short*)(ws + off); // 3*NBIN*128*2 = 50.3 MiB

  hipMemsetAsync(cntb, 0, (size_t)3 * NBIN * 4, stream);
  k_idxcount<<<BTOT / 256, 256, 0, stream>>>(p, idx, cntb);
  k_scan<<<3, 1024, 0, stream>>>(cntb, starts, cursor);
  k_place<<<3 * BTOT / 256, 256, 0, stream>>>(idx, cursor, plist);
  k_pack<<<200, 256, 0, stream>>>(bw0, bw1, bws, P1, P2);
  k_packc<<<4, 256, 0, stream>>>(fccw, P3);

  for (int blk = 0; blk < 5; ++blk) {
    if (blk > 0) {
      dim3 g(NBIN / 64, 3);
      k_poolmax<<<g, 256, 0, stream>>>(netA, starts, plist, seg);
    }
    k_resblock<<<BTOT / 32, 256, 0, stream>>>(
        p, fcw, fcb,
        netA, seg, idx, (blk == 0) ? 2 : 1,
        P1 + (size_t)blk * P1_LAYER, P2 + (size_t)blk * P2_LAYER,
        bb0 + (size_t)blk * 128, bb1 + (size_t)blk * 128,
        P3, fccb, (blk == 4) ? cbuf : (unsigned short*)nullptr);
  }

  dim3 gm(R2_ / 64, 12);
  k_meanout<<<gm, 256, 0, stream>>>(cbuf, starts, plist, out);
}